// Round 7
// baseline (29.462 us; speedup 1.0000x reference)
//
#include <hip/hip_runtime.h>

// Soft decision forest, depth=4, W=4: B=256, T=64, N=341 nodes, 1024 leaves.
// out[bt, j0*256+j1*64+j2*16+j3*4+j4] = prod softmax(in[bt, n_l, :])[j_l]
// preorder: n0=0, n1=1+85*j0, n2=n1+1+21*j1, n3=n2+1+5*j2, n4=n3+1+j3.
//
// Persistent grid-stride variant: 2048 blocks (8/CU resident), 8 bt each,
// double-buffered LDS; next tile's global loads issued BEFORE the barrier so
// HBM reads stream continuously per wave (ILP on top of TLP), and the 8x
// block launch/retire ramp of the 16384-block version disappears.

#define NUM_NODES 341
#define GRID 2048
#define ITERS 8   // 16384 / 2048

__global__ __launch_bounds__(256) void forest_kernel(const float* __restrict__ in,
                                                     float* __restrict__ out) {
    __shared__ float4 sP[2][NUM_NODES];   // 10912 B: double-buffered prob tables

    const int tid = threadIdx.x;
    const bool tail = (tid < NUM_NODES - 256);   // 85 threads load the 2nd row

    const int j0 =  tid >> 6;
    const int j1 = (tid >> 4) & 3;
    const int j2 = (tid >> 2) & 3;
    const int j3 =  tid & 3;
    const int n1 = 1 + j0 * 85;
    const int n2 = n1 + 1 + j1 * 21;
    const int n3 = n2 + 1 + j2 * 5;
    const int n4 = n3 + 1 + j3;

    // Prologue: load tile 0
    const float4* in4 = reinterpret_cast<const float4*>(in);
    size_t bt = blockIdx.x;
    float4 v0 = in4[bt * NUM_NODES + tid];
    float4 v1 = tail ? in4[bt * NUM_NODES + 256 + tid] : make_float4(0, 0, 0, 0);

    int buf = 0;
#pragma unroll
    for (int i = 0; i < ITERS; ++i) {
        // ---- Phase 1: softmax current tile's rows into sP[buf] ----
        {
            float4 x = v0;
            float m  = fmaxf(fmaxf(x.x, x.y), fmaxf(x.z, x.w));
            float e0 = __expf(x.x - m), e1 = __expf(x.y - m);
            float e2 = __expf(x.z - m), e3 = __expf(x.w - m);
            float r  = 1.0f / (e0 + e1 + e2 + e3);
            sP[buf][tid] = make_float4(e0 * r, e1 * r, e2 * r, e3 * r);
        }
        if (tail) {
            float4 x = v1;
            float m  = fmaxf(fmaxf(x.x, x.y), fmaxf(x.z, x.w));
            float e0 = __expf(x.x - m), e1 = __expf(x.y - m);
            float e2 = __expf(x.z - m), e3 = __expf(x.w - m);
            float r  = 1.0f / (e0 + e1 + e2 + e3);
            sP[buf][256 + tid] = make_float4(e0 * r, e1 * r, e2 * r, e3 * r);
        }

        // ---- Prefetch next tile BEFORE the barrier (overlaps barrier+phase2) ----
        if (i < ITERS - 1) {
            const size_t btn = bt + GRID;
            v0 = in4[btn * NUM_NODES + tid];
            if (tail) v1 = in4[btn * NUM_NODES + 256 + tid];
        }

        __syncthreads();

        // ---- Phase 2: 4 leaves per thread from sP[buf], coalesced store ----
        const float* sPf = reinterpret_cast<const float*>(sP[buf]);
        const float pre = sPf[j0]
                        * sPf[n1 * 4 + j1]
                        * sPf[n2 * 4 + j2]
                        * sPf[n3 * 4 + j3];
        float4 pv = sP[buf][n4];
        reinterpret_cast<float4*>(out)[bt * 256 + tid] =
            make_float4(pre * pv.x, pre * pv.y, pre * pv.z, pre * pv.w);

        bt += GRID;
        buf ^= 1;
        // No second barrier needed: phase2 reads of sP[b] in iter i are
        // ordered before phase1 writes of sP[b] in iter i+2 by the iter-i+1
        // barrier (alternating buffers).
    }
}

extern "C" void kernel_launch(void* const* d_in, const int* in_sizes, int n_in,
                              void* d_out, int out_size, void* d_ws, size_t ws_size,
                              hipStream_t stream) {
    const float* in = (const float*)d_in[0];
    float* out = (float*)d_out;
    forest_kernel<<<GRID, 256, 0, stream>>>(in, out);
}

// Round 8
// 28.370 us; speedup vs baseline: 1.0385x; 1.0385x over previous
//
#include <hip/hip_runtime.h>

// Soft decision forest, depth=4, W=4: B=256, T=64, N=341 nodes, 1024 leaves.
// Output[b,t,L] = prod_{l=0..4} softmax(in[b,t,n_l,:])[j_l],
// L = j0*256 + j1*64 + j2*16 + j3*4 + j4, preorder node indices:
// n0=0, n1=1+85*j0, n2=n1+1+21*j1, n3=n2+1+5*j2, n4=n3+1+j3.
//
// FINAL (R1 structure): block-per-bt, LDS softmax table, plain cached
// float4 ld/st. 28.34 us = 88% of the 6.29 TB/s copy ceiling for the
// mandatory 156.5 MB single-touch traffic. A/B-tested and rejected:
// wave-private-LDS/no-barrier (neutral), register-gather (+9%),
// nontemporal ld/st (+8%), persistent grid + LDS double-buffer (+4%).

#define NUM_NODES 341

__global__ __launch_bounds__(256) void forest_kernel(const float* __restrict__ in,
                                                     float* __restrict__ out) {
    __shared__ float4 sP[NUM_NODES];  // 5456 B: softmax probs per node

    const int bt  = blockIdx.x;       // (b*T + t), 0..16383
    const int tid = threadIdx.x;      // 0..255

    // ---- Phase 1: softmax over W=4 per node, coalesced float4 loads ----
    const float4* in4 = reinterpret_cast<const float4*>(in) + (size_t)bt * NUM_NODES;
    for (int n = tid; n < NUM_NODES; n += 256) {
        float4 v = in4[n];
        float m  = fmaxf(fmaxf(v.x, v.y), fmaxf(v.z, v.w));
        float e0 = __expf(v.x - m);
        float e1 = __expf(v.y - m);
        float e2 = __expf(v.z - m);
        float e3 = __expf(v.w - m);
        float r  = 1.0f / (e0 + e1 + e2 + e3);
        sP[n] = make_float4(e0 * r, e1 * r, e2 * r, e3 * r);
    }
    __syncthreads();

    // ---- Phase 2: each thread computes 4 consecutive leaves (shared n4) ----
    const float* sPf = reinterpret_cast<const float*>(sP);
    const int j0 =  tid >> 6;
    const int j1 = (tid >> 4) & 3;
    const int j2 = (tid >> 2) & 3;
    const int j3 =  tid & 3;

    const int n1 = 1 + j0 * 85;
    const int n2 = n1 + 1 + j1 * 21;
    const int n3 = n2 + 1 + j2 * 5;
    const int n4 = n3 + 1 + j3;

    const float pre = sPf[j0]            // root node 0, branch j0
                    * sPf[n1 * 4 + j1]
                    * sPf[n2 * 4 + j2]
                    * sPf[n3 * 4 + j3];

    float4 pv = sP[n4];
    float4 o  = make_float4(pre * pv.x, pre * pv.y, pre * pv.z, pre * pv.w);

    reinterpret_cast<float4*>(out)[(size_t)bt * 256 + tid] = o;
}

extern "C" void kernel_launch(void* const* d_in, const int* in_sizes, int n_in,
                              void* d_out, int out_size, void* d_ws, size_t ws_size,
                              hipStream_t stream) {
    const float* in = (const float*)d_in[0];
    float* out = (float*)d_out;
    const int num_bt = 256 * 64;  // B * T
    forest_kernel<<<num_bt, 256, 0, stream>>>(in, out);
}